// Round 1
// baseline (596.749 us; speedup 1.0000x reference)
//
#include <hip/hip_runtime.h>
#include <stdint.h>

// dx/dt = F - B*x - r * rowsum(x * (A@x))  broadcast over DIM
// A: 10000x10000 f32 (streamed once, 400MB -> memory bound ~63.5us floor)
// x: 10000x64 f32. Compute A@x with bf16 MFMA (threshold 20.64 >> bf16 error).

#define N_ROWS 10000
#define DIM 64
#define KTILE 32
#define NKT 313  // ceil(10000/32); K padded to 10016 with zeros in packed B
#define F_CONST 1.0f
#define B_CONST 0.1f
#define R_CONST 0.01f

typedef __attribute__((ext_vector_type(8))) short s16x8;   // 8 bf16 (MFMA A/B frag)
typedef __attribute__((ext_vector_type(4))) float f32x4;   // MFMA C/D frag
typedef __attribute__((ext_vector_type(4))) uint32_t u32x4;

// round-to-nearest f32 -> bf16, packed pair into one u32
__device__ __forceinline__ uint32_t pack_bf16(float a, float b) {
    uint32_t ua = __builtin_bit_cast(uint32_t, a);
    uint32_t ub = __builtin_bit_cast(uint32_t, b);
    ua += 0x7FFFu + ((ua >> 16) & 1u);
    ub += 0x7FFFu + ((ub >> 16) & 1u);
    return (ua >> 16) | (ub & 0xFFFF0000u);
}

// Pack x into per-lane-contiguous MFMA B fragments (bf16), zero-padded past K=10000.
// Fragment id = t*4 + c (t: ktile 0..312, c: 16-col tile 0..3).
// Lane L holds B[k = t*32 + (L>>4)*8 + j][col = c*16 + (L&15)], j=0..7 -> 16B.
__global__ __launch_bounds__(256) void pack_x_kernel(const float* __restrict__ x,
                                                     uint32_t* __restrict__ ws) {
    int id = blockIdx.x * 256 + threadIdx.x;  // 0 .. 313*4*64-1 = 80127
    int frag = id >> 6;
    int L = id & 63;
    int t = frag >> 2;
    int c = frag & 3;
    int k0 = t * KTILE + (L >> 4) * 8;
    int col = c * 16 + (L & 15);
    float v[8];
#pragma unroll
    for (int j = 0; j < 8; ++j) {
        int k = k0 + j;
        v[j] = (k < N_ROWS) ? x[k * DIM + col] : 0.0f;
    }
    u32x4 p;
    p.x = pack_bf16(v[0], v[1]);
    p.y = pack_bf16(v[2], v[3]);
    p.z = pack_bf16(v[4], v[5]);
    p.w = pack_bf16(v[6], v[7]);
    ((u32x4*)ws)[id] = p;
}

// One block = 16 output rows. 4 waves split K round-robin; LDS reduce; fused epilogue.
__global__ __launch_bounds__(256, 4) void gemm_diffuse_kernel(
    const float* __restrict__ A, const float* __restrict__ x,
    const uint32_t* __restrict__ ws, float* __restrict__ out) {
    __shared__ float red[4][16][DIM];  // 16 KB

    int tid = threadIdx.x;
    int w = tid >> 6;       // wave 0..3
    int L = tid & 63;       // lane
    int quad = L >> 4;      // 0..3
    int m = L & 15;         // row-in-tile for A frag / col for B frag
    int rbase = blockIdx.x * 16;
    const float* Arow = A + (size_t)(rbase + m) * N_ROWS;

    f32x4 acc[4] = {{0.f, 0.f, 0.f, 0.f},
                    {0.f, 0.f, 0.f, 0.f},
                    {0.f, 0.f, 0.f, 0.f},
                    {0.f, 0.f, 0.f, 0.f}};

    for (int t = w; t < NKT; t += 4) {
        int kg = t * KTILE + quad * 8;
        int ks = (kg < N_ROWS) ? kg : 0;  // pad-safe: B frag is 0 there
        // A fragment: 8 consecutive fp32 of this lane's row (nontemporal: A is
        // read once; keep packed x hot in L2).
        f32x4 a0 = __builtin_nontemporal_load((const f32x4*)(Arow + ks));
        f32x4 a1 = __builtin_nontemporal_load(((const f32x4*)(Arow + ks)) + 1);
        u32x4 pa;
        pa.x = pack_bf16(a0.x, a0.y);
        pa.y = pack_bf16(a0.z, a0.w);
        pa.z = pack_bf16(a1.x, a1.y);
        pa.w = pack_bf16(a1.z, a1.w);
        s16x8 afrag = __builtin_bit_cast(s16x8, pa);

        const u32x4* pb = (const u32x4*)ws + (size_t)(t * 4) * 64 + L;
#pragma unroll
        for (int c = 0; c < 4; ++c) {
            s16x8 bfrag = __builtin_bit_cast(s16x8, pb[c * 64]);
            acc[c] = __builtin_amdgcn_mfma_f32_16x16x32_bf16(afrag, bfrag, acc[c], 0, 0, 0);
        }
    }

    // stash per-wave partial Ax tiles (C/D layout: row = quad*4+r, col = c*16+m)
#pragma unroll
    for (int c = 0; c < 4; ++c)
#pragma unroll
        for (int r = 0; r < 4; ++r)
            red[w][quad * 4 + r][c * 16 + m] = acc[c][r];
    __syncthreads();

    // epilogue: thread t -> row = t>>4 (0..15), 4 cols starting at (t&15)*4
    int row = tid >> 4;
    int q = tid & 15;
    int grow = rbase + row;
    f32x4 xv = *(const f32x4*)(x + (size_t)grow * DIM + q * 4);
    f32x4 axv;
#pragma unroll
    for (int j = 0; j < 4; ++j)
        axv[j] = red[0][row][q * 4 + j] + red[1][row][q * 4 + j] +
                 red[2][row][q * 4 + j] + red[3][row][q * 4 + j];
    float partial = xv.x * axv[0] + xv.y * axv[1] + xv.z * axv[2] + xv.w * axv[3];
    // reduce over the 16 threads covering this row (xor masks stay in 16-groups)
    partial += __shfl_xor(partial, 1);
    partial += __shfl_xor(partial, 2);
    partial += __shfl_xor(partial, 4);
    partial += __shfl_xor(partial, 8);
    float s = R_CONST * partial;

    f32x4 o;
    o.x = F_CONST - B_CONST * xv.x - s;
    o.y = F_CONST - B_CONST * xv.y - s;
    o.z = F_CONST - B_CONST * xv.z - s;
    o.w = F_CONST - B_CONST * xv.w - s;
    *(f32x4*)(out + (size_t)grow * DIM + q * 4) = o;
}

extern "C" void kernel_launch(void* const* d_in, const int* in_sizes, int n_in,
                              void* d_out, int out_size, void* d_ws, size_t ws_size,
                              hipStream_t stream) {
    // inputs: t (1, unused), x (10000*64 f32), A (10000*10000 f32)
    const float* x = (const float*)d_in[1];
    const float* A = (const float*)d_in[2];
    float* out = (float*)d_out;
    uint32_t* ws = (uint32_t*)d_ws;  // 80128 * 16B = ~1.22 MiB packed bf16 x

    pack_x_kernel<<<313, 256, 0, stream>>>(x, ws);
    gemm_diffuse_kernel<<<625, 256, 0, stream>>>(A, x, ws, out);
}

// Round 2
// 586.641 us; speedup vs baseline: 1.0172x; 1.0172x over previous
//
#include <hip/hip_runtime.h>
#include <stdint.h>

// dx/dt = F - B*x - r * rowsum(x * (A@x))  broadcast over DIM
// A: 10000x10000 f32 streamed once (400MB -> ~63.5us HBM floor).
// A@x via bf16 MFMA 16x16x32 (absmax 4.0 vs threshold 20.64 — verified R1).
// R2: 2500 blocks (625 row-tiles x 4 K-quarters), per-wave shuffle-reduced
// partial row-dot + global atomicAdd (linear in K-partials), no LDS/barrier.

#define N_ROWS 10000
#define DIM 64
#define KTILE 32
#define NKT 313  // ceil(10000/32); K padded to 10016 with zeros in packed B
#define F_CONST 1.0f
#define B_CONST 0.1f
#define R_CONST 0.01f

#define SACC_OFF_BYTES 1310720  // packed B ends at 80128*16 = 1282048

typedef __attribute__((ext_vector_type(8))) short s16x8;   // 8 bf16 (MFMA A/B frag)
typedef __attribute__((ext_vector_type(4))) float f32x4;   // MFMA C/D frag
typedef __attribute__((ext_vector_type(4))) uint32_t u32x4;

// round-to-nearest f32 -> bf16, packed pair into one u32
__device__ __forceinline__ uint32_t pack_bf16(float a, float b) {
    uint32_t ua = __builtin_bit_cast(uint32_t, a);
    uint32_t ub = __builtin_bit_cast(uint32_t, b);
    ua += 0x7FFFu + ((ua >> 16) & 1u);
    ub += 0x7FFFu + ((ub >> 16) & 1u);
    return (ua >> 16) | (ub & 0xFFFF0000u);
}

// Pack x into per-lane-contiguous MFMA B fragments (bf16), zero-padded past K=10000.
// Fragment id = t*4 + c. Lane L holds B[k=t*32+(L>>4)*8+j][col=c*16+(L&15)], j=0..7.
// Also zeroes the per-row dot accumulator (ws is re-poisoned 0xAA every call).
__global__ __launch_bounds__(256) void pack_x_kernel(const float* __restrict__ x,
                                                     uint32_t* __restrict__ ws,
                                                     float* __restrict__ sacc) {
    int id = blockIdx.x * 256 + threadIdx.x;  // 0 .. 80127
    if (id < N_ROWS) sacc[id] = 0.0f;
    int frag = id >> 6;
    int L = id & 63;
    int t = frag >> 2;
    int c = frag & 3;
    int k0 = t * KTILE + (L >> 4) * 8;
    int col = c * 16 + (L & 15);
    float v[8];
#pragma unroll
    for (int j = 0; j < 8; ++j) {
        int k = k0 + j;
        v[j] = (k < N_ROWS) ? x[k * DIM + col] : 0.0f;
    }
    u32x4 p;
    p.x = pack_bf16(v[0], v[1]);
    p.y = pack_bf16(v[2], v[3]);
    p.z = pack_bf16(v[4], v[5]);
    p.w = pack_bf16(v[6], v[7]);
    ((u32x4*)ws)[id] = p;
}

// blockIdx.x = row tile (16 rows), blockIdx.y = K quarter. 4 waves split the
// quarter's k-tiles round-robin. Each wave computes its partial Ax tile in
// AGPR/VGPR, dots it with x, shuffle-reduces within 16-lane groups, and
// atomicAdds 16 partial scalars. No LDS, no __syncthreads.
__global__ __launch_bounds__(256, 4) void gemm_dot_kernel(
    const float* __restrict__ A, const float* __restrict__ x,
    const uint32_t* __restrict__ ws, float* __restrict__ sacc) {
    int tid = threadIdx.x;
    int w = tid >> 6;       // wave 0..3
    int L = tid & 63;       // lane
    int quad = L >> 4;      // 0..3
    int m = L & 15;         // row-in-tile for A frag / col-in-16 for B frag
    int rbase = blockIdx.x * 16;
    int q = blockIdx.y;     // K quarter
    int t0 = q * 79;
    int t1 = (q == 3) ? NKT : (t0 + 79);
    const float* Arow = A + (size_t)(rbase + m) * N_ROWS;

    f32x4 acc[4] = {{0.f, 0.f, 0.f, 0.f},
                    {0.f, 0.f, 0.f, 0.f},
                    {0.f, 0.f, 0.f, 0.f},
                    {0.f, 0.f, 0.f, 0.f}};

    for (int t = t0 + w; t < t1; t += 4) {
        int kg = t * KTILE + quad * 8;
        int ks = (kg < N_ROWS) ? kg : 0;  // pad-safe: B frag is 0 there
        f32x4 a0 = __builtin_nontemporal_load((const f32x4*)(Arow + ks));
        f32x4 a1 = __builtin_nontemporal_load(((const f32x4*)(Arow + ks)) + 1);
        const u32x4* pb = (const u32x4*)ws + (size_t)(t * 4) * 64 + L;
        u32x4 pa;
        pa.x = pack_bf16(a0.x, a0.y);
        pa.y = pack_bf16(a0.z, a0.w);
        pa.z = pack_bf16(a1.x, a1.y);
        pa.w = pack_bf16(a1.z, a1.w);
        s16x8 afrag = __builtin_bit_cast(s16x8, pa);
#pragma unroll
        for (int c = 0; c < 4; ++c) {
            s16x8 bfrag = __builtin_bit_cast(s16x8, pb[c * 64]);
            acc[c] = __builtin_amdgcn_mfma_f32_16x16x32_bf16(afrag, bfrag, acc[c], 0, 0, 0);
        }
    }

    // Per-wave epilogue. C/D layout: acc[c][r] = Ax[row=quad*4+r][col=c*16+m].
    // p[r] = sum_c Ax[row][c*16+m] * x[grow][c*16+m]; reduce over m (16 lanes).
    float p[4];
#pragma unroll
    for (int r = 0; r < 4; ++r) {
        int grow = rbase + quad * 4 + r;
        const float* xr = x + (size_t)grow * DIM + m;
        p[r] = acc[0][r] * xr[0] + acc[1][r] * xr[16] +
               acc[2][r] * xr[32] + acc[3][r] * xr[48];
        p[r] += __shfl_xor(p[r], 1);
        p[r] += __shfl_xor(p[r], 2);
        p[r] += __shfl_xor(p[r], 4);
        p[r] += __shfl_xor(p[r], 8);
    }
    if (m == 0) {
#pragma unroll
        for (int r = 0; r < 4; ++r)
            atomicAdd(&sacc[rbase + quad * 4 + r], p[r]);
    }
}

__global__ __launch_bounds__(256) void finalize_kernel(const float* __restrict__ x,
                                                       const float* __restrict__ sacc,
                                                       float* __restrict__ out) {
    int id = blockIdx.x * 256 + threadIdx.x;  // 0 .. 159999 (f32x4 units)
    f32x4 xv = ((const f32x4*)x)[id];
    float s = R_CONST * sacc[id >> 4];
    f32x4 o;
    o.x = F_CONST - B_CONST * xv.x - s;
    o.y = F_CONST - B_CONST * xv.y - s;
    o.z = F_CONST - B_CONST * xv.z - s;
    o.w = F_CONST - B_CONST * xv.w - s;
    ((f32x4*)out)[id] = o;
}

extern "C" void kernel_launch(void* const* d_in, const int* in_sizes, int n_in,
                              void* d_out, int out_size, void* d_ws, size_t ws_size,
                              hipStream_t stream) {
    // inputs: t (1, unused), x (10000*64 f32), A (10000*10000 f32)
    const float* x = (const float*)d_in[1];
    const float* A = (const float*)d_in[2];
    float* out = (float*)d_out;
    uint32_t* ws = (uint32_t*)d_ws;  // [0, 1.22MB): packed bf16 x fragments
    float* sacc = (float*)((char*)d_ws + SACC_OFF_BYTES);  // 40KB row-dot acc

    pack_x_kernel<<<313, 256, 0, stream>>>(x, ws, sacc);
    gemm_dot_kernel<<<dim3(625, 4), 256, 0, stream>>>(A, x, ws, sacc);
    finalize_kernel<<<625, 256, 0, stream>>>(x, sacc, out);
}

// Round 3
// 586.105 us; speedup vs baseline: 1.0182x; 1.0009x over previous
//
#include <hip/hip_runtime.h>
#include <stdint.h>

// dx/dt = F - B*x - r * rowsum(x * (A@x))  broadcast over DIM
// A: 10000x10000 f32 streamed once (400MB -> ~63.5us HBM floor).
// A@x via bf16 MFMA 16x16x32 (absmax 4.0 vs threshold 20.64 — verified R1).
// R3: K-loop unrolled x4, all 8 A dwordx4 loads issued before consumption —
// 4x per-wave in-flight HBM bytes (Little's-law fix for the ~2 TB/s plateau).

#define N_ROWS 10000
#define DIM 64
#define KTILE 32
#define NKT 313  // ceil(10000/32); K padded to 10016 with zeros in packed B
#define F_CONST 1.0f
#define B_CONST 0.1f
#define R_CONST 0.01f

#define SACC_OFF_BYTES 1310720  // packed B ends at 80128*16 = 1282048

typedef __attribute__((ext_vector_type(8))) short s16x8;   // 8 bf16 (MFMA A/B frag)
typedef __attribute__((ext_vector_type(4))) float f32x4;   // MFMA C/D frag
typedef __attribute__((ext_vector_type(4))) uint32_t u32x4;

// round-to-nearest f32 -> bf16, packed pair into one u32
__device__ __forceinline__ uint32_t pack_bf16(float a, float b) {
    uint32_t ua = __builtin_bit_cast(uint32_t, a);
    uint32_t ub = __builtin_bit_cast(uint32_t, b);
    ua += 0x7FFFu + ((ua >> 16) & 1u);
    ub += 0x7FFFu + ((ub >> 16) & 1u);
    return (ua >> 16) | (ub & 0xFFFF0000u);
}

// Pack x into per-lane-contiguous MFMA B fragments (bf16), zero-padded past K=10000.
// Fragment id = t*4 + c. Lane L holds B[k=t*32+(L>>4)*8+j][col=c*16+(L&15)], j=0..7.
// Also zeroes the per-row dot accumulator (ws is re-poisoned 0xAA every call).
__global__ __launch_bounds__(256) void pack_x_kernel(const float* __restrict__ x,
                                                     uint32_t* __restrict__ ws,
                                                     float* __restrict__ sacc) {
    int id = blockIdx.x * 256 + threadIdx.x;  // 0 .. 80127
    if (id < N_ROWS) sacc[id] = 0.0f;
    int frag = id >> 6;
    int L = id & 63;
    int t = frag >> 2;
    int c = frag & 3;
    int k0 = t * KTILE + (L >> 4) * 8;
    int col = c * 16 + (L & 15);
    float v[8];
#pragma unroll
    for (int j = 0; j < 8; ++j) {
        int k = k0 + j;
        v[j] = (k < N_ROWS) ? x[k * DIM + col] : 0.0f;
    }
    u32x4 p;
    p.x = pack_bf16(v[0], v[1]);
    p.y = pack_bf16(v[2], v[3]);
    p.z = pack_bf16(v[4], v[5]);
    p.w = pack_bf16(v[6], v[7]);
    ((u32x4*)ws)[id] = p;
}

// blockIdx.x = row tile (16 rows), blockIdx.y = K quarter. 4 waves round-robin
// the quarter's k-tiles; K-loop unrolled x4 (tiles t, t+4, t+8, t+12) with all
// A loads issued before any consumption. Per-wave epilogue: dot with x,
// 16-lane shuffle reduce, atomicAdd partial scalars. No LDS, no barriers.
__global__ __launch_bounds__(256, 4) void gemm_dot_kernel(
    const float* __restrict__ A, const float* __restrict__ x,
    const uint32_t* __restrict__ ws, float* __restrict__ sacc) {
    int tid = threadIdx.x;
    int w = tid >> 6;       // wave 0..3
    int L = tid & 63;       // lane
    int quad = L >> 4;      // 0..3
    int m = L & 15;         // row-in-tile for A frag / col-in-16 for B frag
    int rbase = blockIdx.x * 16;
    int q = blockIdx.y;     // K quarter
    int t0 = q * 79;
    int t1 = (q == 3) ? NKT : (t0 + 79);
    const float* Arow = A + (size_t)(rbase + m) * N_ROWS;

    f32x4 acc[4] = {{0.f, 0.f, 0.f, 0.f},
                    {0.f, 0.f, 0.f, 0.f},
                    {0.f, 0.f, 0.f, 0.f},
                    {0.f, 0.f, 0.f, 0.f}};

    int t = t0 + w;
    // Unrolled-by-4: batch-issue 8 A dwordx4 loads (tiles t, t+4, t+8, t+12),
    // keeping later groups in flight while packing/MFMAing earlier ones.
    for (; t + 12 < t1; t += 16) {
        f32x4 a0[4], a1[4];
#pragma unroll
        for (int u = 0; u < 4; ++u) {
            int kg = (t + 4 * u) * KTILE + quad * 8;
            int ks = (kg < N_ROWS) ? kg : 0;  // pad-safe: B frag is 0 there
            a0[u] = __builtin_nontemporal_load((const f32x4*)(Arow + ks));
            a1[u] = __builtin_nontemporal_load(((const f32x4*)(Arow + ks)) + 1);
        }
#pragma unroll
        for (int u = 0; u < 4; ++u) {
            int tt = t + 4 * u;
            const u32x4* pb = (const u32x4*)ws + (size_t)(tt * 4) * 64 + L;
            u32x4 pa;
            pa.x = pack_bf16(a0[u].x, a0[u].y);
            pa.y = pack_bf16(a0[u].z, a0[u].w);
            pa.z = pack_bf16(a1[u].x, a1[u].y);
            pa.w = pack_bf16(a1[u].z, a1[u].w);
            s16x8 afrag = __builtin_bit_cast(s16x8, pa);
#pragma unroll
            for (int c = 0; c < 4; ++c) {
                s16x8 bfrag = __builtin_bit_cast(s16x8, pb[c * 64]);
                acc[c] = __builtin_amdgcn_mfma_f32_16x16x32_bf16(afrag, bfrag, acc[c], 0, 0, 0);
            }
        }
    }
    // remainder tiles
    for (; t < t1; t += 4) {
        int kg = t * KTILE + quad * 8;
        int ks = (kg < N_ROWS) ? kg : 0;
        f32x4 a0 = __builtin_nontemporal_load((const f32x4*)(Arow + ks));
        f32x4 a1 = __builtin_nontemporal_load(((const f32x4*)(Arow + ks)) + 1);
        const u32x4* pb = (const u32x4*)ws + (size_t)(t * 4) * 64 + L;
        u32x4 pa;
        pa.x = pack_bf16(a0.x, a0.y);
        pa.y = pack_bf16(a0.z, a0.w);
        pa.z = pack_bf16(a1.x, a1.y);
        pa.w = pack_bf16(a1.z, a1.w);
        s16x8 afrag = __builtin_bit_cast(s16x8, pa);
#pragma unroll
        for (int c = 0; c < 4; ++c) {
            s16x8 bfrag = __builtin_bit_cast(s16x8, pb[c * 64]);
            acc[c] = __builtin_amdgcn_mfma_f32_16x16x32_bf16(afrag, bfrag, acc[c], 0, 0, 0);
        }
    }

    // Per-wave epilogue. C/D layout: acc[c][r] = Ax[row=quad*4+r][col=c*16+m].
    float p[4];
#pragma unroll
    for (int r = 0; r < 4; ++r) {
        int grow = rbase + quad * 4 + r;
        const float* xr = x + (size_t)grow * DIM + m;
        p[r] = acc[0][r] * xr[0] + acc[1][r] * xr[16] +
               acc[2][r] * xr[32] + acc[3][r] * xr[48];
        p[r] += __shfl_xor(p[r], 1);
        p[r] += __shfl_xor(p[r], 2);
        p[r] += __shfl_xor(p[r], 4);
        p[r] += __shfl_xor(p[r], 8);
    }
    if (m == 0) {
#pragma unroll
        for (int r = 0; r < 4; ++r)
            atomicAdd(&sacc[rbase + quad * 4 + r], p[r]);
    }
}

__global__ __launch_bounds__(256) void finalize_kernel(const float* __restrict__ x,
                                                       const float* __restrict__ sacc,
                                                       float* __restrict__ out) {
    int id = blockIdx.x * 256 + threadIdx.x;  // 0 .. 159999 (f32x4 units)
    f32x4 xv = ((const f32x4*)x)[id];
    float s = R_CONST * sacc[id >> 4];
    f32x4 o;
    o.x = F_CONST - B_CONST * xv.x - s;
    o.y = F_CONST - B_CONST * xv.y - s;
    o.z = F_CONST - B_CONST * xv.z - s;
    o.w = F_CONST - B_CONST * xv.w - s;
    ((f32x4*)out)[id] = o;
}

extern "C" void kernel_launch(void* const* d_in, const int* in_sizes, int n_in,
                              void* d_out, int out_size, void* d_ws, size_t ws_size,
                              hipStream_t stream) {
    // inputs: t (1, unused), x (10000*64 f32), A (10000*10000 f32)
    const float* x = (const float*)d_in[1];
    const float* A = (const float*)d_in[2];
    float* out = (float*)d_out;
    uint32_t* ws = (uint32_t*)d_ws;  // [0, 1.22MB): packed bf16 x fragments
    float* sacc = (float*)((char*)d_ws + SACC_OFF_BYTES);  // 40KB row-dot acc

    pack_x_kernel<<<313, 256, 0, stream>>>(x, ws, sacc);
    gemm_dot_kernel<<<dim3(625, 4), 256, 0, stream>>>(A, x, ws, sacc);
    finalize_kernel<<<625, 256, 0, stream>>>(x, sacc, out);
}

// Round 4
// 525.651 us; speedup vs baseline: 1.1353x; 1.1150x over previous
//
#include <hip/hip_runtime.h>
#include <stdint.h>

// dx/dt = F - B*x - r * rowsum(x * (A@x))  broadcast over DIM
// A: 10000x10000 f32 streamed once (400MB -> ~63.5us HBM floor).
// A@x via bf16 MFMA 16x16x32 (absmax 4.0 vs threshold 20.64 — verified R1).
// R4: coalesced-staging gemm. Each wave loads 1KB contiguous A per instr,
// packs to bf16, stages in XOR-swizzled LDS (conflict-free), ds_read_b128
// A-frags, double-buffered K-chunks of 256. Discriminates pattern-limited
// (expect ~-120us) vs harness-dominated (expect ~0) worlds.

#define N_ROWS 10000
#define DIM 64
#define KTILE 32
#define NKT 320      // K padded to 10240: 320 tiles of 32; B zero-filled past 10000
#define CHUNK_K 256  // K-chunk staged per block iteration (8 tiles)
#define CHUNKS_PER_Y 20
#define F_CONST 1.0f
#define B_CONST 0.1f
#define R_CONST 0.01f

#define SACC_OFF_BYTES 1310720  // packed B ends at 320*4*64*16 = 1310720

typedef __attribute__((ext_vector_type(8))) short s16x8;   // 8 bf16 (MFMA A/B frag)
typedef __attribute__((ext_vector_type(4))) float f32x4;   // MFMA C/D frag
typedef __attribute__((ext_vector_type(4))) uint32_t u32x4;
typedef __attribute__((ext_vector_type(2))) uint32_t u32x2;

// round-to-nearest f32 -> bf16, packed pair into one u32
__device__ __forceinline__ uint32_t pack_bf16(float a, float b) {
    uint32_t ua = __builtin_bit_cast(uint32_t, a);
    uint32_t ub = __builtin_bit_cast(uint32_t, b);
    ua += 0x7FFFu + ((ua >> 16) & 1u);
    ub += 0x7FFFu + ((ub >> 16) & 1u);
    return (ua >> 16) | (ub & 0xFFFF0000u);
}

// Pack x into per-lane-contiguous MFMA B fragments (bf16), zero-padded past K=10000.
// Fragment id = t*4 + c, t in [0,320). Lane L holds B[k=t*32+(L>>4)*8+j][col=c*16+(L&15)].
// Also zeroes the per-row dot accumulator (ws is re-poisoned 0xAA every call).
__global__ __launch_bounds__(256) void pack_x_kernel(const float* __restrict__ x,
                                                     uint32_t* __restrict__ ws,
                                                     float* __restrict__ sacc) {
    int id = blockIdx.x * 256 + threadIdx.x;  // 0 .. 81919
    if (id < N_ROWS) sacc[id] = 0.0f;
    int frag = id >> 6;
    int L = id & 63;
    int t = frag >> 2;
    int c = frag & 3;
    int k0 = t * KTILE + (L >> 4) * 8;
    int col = c * 16 + (L & 15);
    float v[8];
#pragma unroll
    for (int j = 0; j < 8; ++j) {
        int k = k0 + j;
        v[j] = (k < N_ROWS) ? x[k * DIM + col] : 0.0f;
    }
    u32x4 p;
    p.x = pack_bf16(v[0], v[1]);
    p.y = pack_bf16(v[2], v[3]);
    p.z = pack_bf16(v[4], v[5]);
    p.w = pack_bf16(v[6], v[7]);
    ((u32x4*)ws)[id] = p;
}

// blockIdx.x = row tile (16 rows), blockIdx.y = K half (20 chunks of 256 each).
// Per chunk: 4 waves cooperatively stage 16 rows x 256 k of A (1KB contiguous
// per wave-instr), bf16-pack, write to XOR-swizzled LDS; then each wave MFMAs
// 2 of the 8 K-tiles. Double-buffered, 1 barrier/chunk. Epilogue: per-wave
// x-dot + 16-lane shuffle reduce + atomicAdd (linear in K-partials).
__global__ __launch_bounds__(256, 4) void gemm_dot_kernel(
    const float* __restrict__ A, const float* __restrict__ x,
    const uint32_t* __restrict__ ws, float* __restrict__ sacc) {
    // bf16 tile [16 rows][256 k], row stride 512B = 32 16B-units.
    // Swizzle: 16B-unit u of row r stored at u ^ (r & 7). Verified uniform
    // bank occupancy for both ds_write_b64 staging and ds_read_b128 frags.
    __shared__ __align__(16) unsigned short lds[2][16 * CHUNK_K];

    int tid = threadIdx.x;
    int w = tid >> 6;       // wave 0..3
    int L = tid & 63;       // lane
    int quad = L >> 4;      // 0..3
    int m = L & 15;         // A-row-in-tile / B col-in-16
    int rbase = blockIdx.x * 16;
    int c0 = blockIdx.y * CHUNKS_PER_Y;
    int c1 = c0 + CHUNKS_PER_Y;
    const float* Ab = A + (size_t)rbase * N_ROWS;

    f32x4 acc[4] = {{0.f, 0.f, 0.f, 0.f},
                    {0.f, 0.f, 0.f, 0.f},
                    {0.f, 0.f, 0.f, 0.f},
                    {0.f, 0.f, 0.f, 0.f}};

    // ---- prologue: stage chunk c0 into buf 0 ----
    {
        f32x4 ld[4];
#pragma unroll
        for (int i = 0; i < 4; ++i) {
            int row = i * 4 + w;
            int kg = c0 * CHUNK_K + L * 4;
            int ks = (kg <= N_ROWS - 4) ? kg : (N_ROWS - 4);  // finite pad (B=0 there)
            ld[i] = __builtin_nontemporal_load((const f32x4*)(Ab + (size_t)row * N_ROWS + ks));
        }
#pragma unroll
        for (int i = 0; i < 4; ++i) {
            int row = i * 4 + w;
            int unit = (L >> 1) ^ (row & 7);
            u32x2 pk;
            pk.x = pack_bf16(ld[i].x, ld[i].y);
            pk.y = pack_bf16(ld[i].z, ld[i].w);
            *(u32x2*)((char*)lds[0] + row * 512 + (unit << 4) + ((L & 1) << 3)) = pk;
        }
    }
    __syncthreads();

    int p = 0;
    for (int c = c0; c < c1; ++c) {
        // issue next chunk's global loads first (overlap with MFMA below)
        f32x4 ld[4];
        bool more = (c + 1 < c1);
        if (more) {
#pragma unroll
            for (int i = 0; i < 4; ++i) {
                int row = i * 4 + w;
                int kg = (c + 1) * CHUNK_K + L * 4;
                int ks = (kg <= N_ROWS - 4) ? kg : (N_ROWS - 4);
                ld[i] = __builtin_nontemporal_load((const f32x4*)(Ab + (size_t)row * N_ROWS + ks));
            }
        }

        // MFMA on buffer p: wave w handles tiles w and w+4 of this chunk
#pragma unroll
        for (int u = 0; u < 2; ++u) {
            int tt = w + 4 * u;
            int T = c * 8 + tt;
            int unit = (tt * 4 + quad) ^ (m & 7);
            s16x8 afrag = *(const s16x8*)((const char*)lds[p] + m * 512 + (unit << 4));
            const u32x4* pb = (const u32x4*)ws + (size_t)T * 256 + L;
#pragma unroll
            for (int cc = 0; cc < 4; ++cc) {
                s16x8 bfrag = __builtin_bit_cast(s16x8, pb[cc * 64]);
                acc[cc] = __builtin_amdgcn_mfma_f32_16x16x32_bf16(afrag, bfrag, acc[cc], 0, 0, 0);
            }
        }

        if (more) {
#pragma unroll
            for (int i = 0; i < 4; ++i) {
                int row = i * 4 + w;
                int unit = (L >> 1) ^ (row & 7);
                u32x2 pk;
                pk.x = pack_bf16(ld[i].x, ld[i].y);
                pk.y = pack_bf16(ld[i].z, ld[i].w);
                *(u32x2*)((char*)lds[p ^ 1] + row * 512 + (unit << 4) + ((L & 1) << 3)) = pk;
            }
        }
        __syncthreads();
        p ^= 1;
    }

    // Per-wave epilogue. C/D layout: acc[cc][r] = Ax_partial[row=quad*4+r][col=cc*16+m].
    float pr[4];
#pragma unroll
    for (int r = 0; r < 4; ++r) {
        int grow = rbase + quad * 4 + r;
        const float* xr = x + (size_t)grow * DIM + m;
        pr[r] = acc[0][r] * xr[0] + acc[1][r] * xr[16] +
                acc[2][r] * xr[32] + acc[3][r] * xr[48];
        pr[r] += __shfl_xor(pr[r], 1);
        pr[r] += __shfl_xor(pr[r], 2);
        pr[r] += __shfl_xor(pr[r], 4);
        pr[r] += __shfl_xor(pr[r], 8);
    }
    if (m == 0) {
#pragma unroll
        for (int r = 0; r < 4; ++r)
            atomicAdd(&sacc[rbase + quad * 4 + r], pr[r]);
    }
}

__global__ __launch_bounds__(256) void finalize_kernel(const float* __restrict__ x,
                                                       const float* __restrict__ sacc,
                                                       float* __restrict__ out) {
    int id = blockIdx.x * 256 + threadIdx.x;  // 0 .. 159999 (f32x4 units)
    f32x4 xv = ((const f32x4*)x)[id];
    float s = R_CONST * sacc[id >> 4];
    f32x4 o;
    o.x = F_CONST - B_CONST * xv.x - s;
    o.y = F_CONST - B_CONST * xv.y - s;
    o.z = F_CONST - B_CONST * xv.z - s;
    o.w = F_CONST - B_CONST * xv.w - s;
    ((f32x4*)out)[id] = o;
}

extern "C" void kernel_launch(void* const* d_in, const int* in_sizes, int n_in,
                              void* d_out, int out_size, void* d_ws, size_t ws_size,
                              hipStream_t stream) {
    // inputs: t (1, unused), x (10000*64 f32), A (10000*10000 f32)
    const float* x = (const float*)d_in[1];
    const float* A = (const float*)d_in[2];
    float* out = (float*)d_out;
    uint32_t* ws = (uint32_t*)d_ws;  // [0, 1.31MB): packed bf16 x fragments (320 tiles)
    float* sacc = (float*)((char*)d_ws + SACC_OFF_BYTES);  // 40KB row-dot acc

    pack_x_kernel<<<320, 256, 0, stream>>>(x, ws, sacc);
    gemm_dot_kernel<<<dim3(625, 2), 256, 0, stream>>>(A, x, ws, sacc);
    finalize_kernel<<<625, 256, 0, stream>>>(x, sacc, out);
}